// Round 5
// baseline (58.493 us; speedup 1.0000x reference)
//
#include <hip/hip_runtime.h>
#include <hip/hip_fp16.h>

#define NI 65536
#define NO 65536
#define NW 32
#define NB 32

typedef float  fx4 __attribute__((ext_vector_type(4)));
typedef int    ix4 __attribute__((ext_vector_type(4)));
typedef uint   ux4 __attribute__((ext_vector_type(4)));
typedef uint   ux2 __attribute__((ext_vector_type(2)));
typedef ushort sx4 __attribute__((ext_vector_type(4)));

// ---- kernel 1: transpose x (B,I) -> xTh fp16 [I][NB]; fwmh = fp16(fw*fm) ----
__global__ __launch_bounds__(256) void dsm_prep(
    const float* __restrict__ x, const float* __restrict__ fw,
    const float* __restrict__ fm, ushort* __restrict__ xTh,
    ushort* __restrict__ fwmh)
{
    __shared__ float tile[32][33];
    const int tid = threadIdx.x;
    const int tx = tid & 31, ty = tid >> 5;
    const int i0 = blockIdx.x * 32;
#pragma unroll
    for (int r = 0; r < 4; ++r) {
        const int b = ty + 8 * r;
        tile[b][tx] = __builtin_nontemporal_load(&x[(size_t)b * NI + i0 + tx]);
    }
    __syncthreads();
#pragma unroll
    for (int r = 0; r < 4; ++r) {
        const int ii = ty + 8 * r;
        xTh[(size_t)(i0 + ii) * NB + tx] =
            __half_as_ushort(__float2half(tile[tx][ii]));
    }
    const size_t base = (size_t)blockIdx.x * 1024 + (size_t)tid * 4;
    const fx4 a = __builtin_nontemporal_load((const fx4*)(fw + base));
    const fx4 m = __builtin_nontemporal_load((const fx4*)(fm + base));
    sx4 h;
    h.x = __half_as_ushort(__float2half(a.x * m.x));
    h.y = __half_as_ushort(__float2half(a.y * m.y));
    h.z = __half_as_ushort(__float2half(a.z * m.z));
    h.w = __half_as_ushort(__float2half(a.w * m.w));
    *(sx4*)(fwmh + base) = h;
}

// ---- kernel 1b: fm bitmap, fmb[i] bit w = (fm[i][w] != 0) ----
__global__ __launch_bounds__(256) void dsm_fmb(
    const float* __restrict__ fm, uint* __restrict__ fmb)
{
    const int tid = threadIdx.x;
    const int wid = tid >> 6, lane = tid & 63;
    // block covers 256 rows; wave covers 64 rows over 32 iterations
    const size_t rowbase = (size_t)blockIdx.x * 256 + (size_t)wid * 64;
    const size_t ebase = rowbase * 32;
#pragma unroll 4
    for (int it = 0; it < 32; ++it) {
        const float v = __builtin_nontemporal_load(&fm[ebase + it * 64 + lane]);
        const unsigned long long m = __ballot(v != 0.0f);
        const uint r0 = (uint)(rowbase + it * 2);
        if (lane == 0)  fmb[r0]     = (uint)m;
        if (lane == 32) fmb[r0 + 1] = (uint)(m >> 32);
    }
}

// ---- kernel 2: per-o-row: drop rm=0, sort by i, drop fm=0, gather fwmh,
//      emit P[o][slot] = (i<<16)|fp16(s)  (zeros = padding: i=0, s=0) ----
template<int USE_FMB>
__global__ __launch_bounds__(256) void dsm_pack(
    const int* __restrict__ om, const float* __restrict__ rm,
    const ushort* __restrict__ fwmh, const uint* __restrict__ fmb,
    uint* __restrict__ P)
{
    __shared__ uint sk[64 * 33];
    const int tid = threadIdx.x;
    const size_t base = (size_t)blockIdx.x * 2048 + (size_t)tid * 8;
    const int r  = tid >> 2;         // row within block (0..63)
    const int w0 = (tid & 3) * 8;    // slot base (0,8,16,24)

    // phase 1: build keys (i<<16 | w<<1 | 1) or sentinel for rm=0
    {
        const ix4 iv0 = __builtin_nontemporal_load((const ix4*)(om + base));
        const ix4 iv1 = __builtin_nontemporal_load((const ix4*)(om + base + 4));
        const fx4 rv0 = __builtin_nontemporal_load((const fx4*)(rm + base));
        const fx4 rv1 = __builtin_nontemporal_load((const fx4*)(rm + base + 4));
#pragma unroll
        for (int j = 0; j < 8; ++j) {
            const uint  i  = (uint)((j < 4) ? iv0[j] : iv1[j - 4]) & 0xffffu;
            const float rv = (j < 4) ? rv0[j] : rv1[j - 4];
            const int   w  = w0 + j;
            sk[r * 33 + w] = (rv != 0.0f)
                ? ((i << 16) | (uint)(w << 1) | 1u) : 0xFFFFFFFFu;
        }
    }
    __syncthreads();

    // phase 2: lanes 0..63 each bitonic-sort one row (ascending; sentinels last)
    if (tid < 64) {
        uint v[32];
#pragma unroll
        for (int k = 0; k < 32; ++k) v[k] = sk[tid * 33 + k];
#pragma unroll
        for (int k = 2; k <= 32; k <<= 1) {
#pragma unroll
            for (int j = k >> 1; j > 0; j >>= 1) {
#pragma unroll
                for (int t = 0; t < 32; ++t) {
                    const int l = t ^ j;
                    if (l > t) {
                        const uint a = v[t], b = v[l];
                        const uint lo = min(a, b), hi = max(a, b);
                        if ((t & k) == 0) { v[t] = lo; v[l] = hi; }
                        else              { v[t] = hi; v[l] = lo; }
                    }
                }
            }
        }
#pragma unroll
        for (int k = 0; k < 32; ++k) sk[tid * 33 + k] = v[k];
    }
    __syncthreads();

    // phase 3: fm check + sorted gather; rewrite slot in place
#pragma unroll
    for (int j = 0; j < 8; ++j) {
        const int s = w0 + j;
        const uint key = sk[r * 33 + s];
        uint p = 0;
        if (key != 0xFFFFFFFFu) {
            const uint i  = key >> 16;
            const uint ww = (key >> 1) & 31u;
            bool keep = true;
            if (USE_FMB) keep = ((fmb[i] >> ww) & 1u) != 0u;
            if (keep) {
                const ushort h = fwmh[i * NW + ww];
                if (USE_FMB || (h & 0x7fffu))   // no-fmb path: drop s==0
                    p = (i << 16) | (uint)h;
            }
        }
        sk[r * 33 + s] = p;
    }
    __syncthreads();

    // phase 4: coalesced nt store of sorted rows
    {
        ux4 a, b;
#pragma unroll
        for (int j = 0; j < 4; ++j) a[j] = sk[r * 33 + w0 + j];
#pragma unroll
        for (int j = 0; j < 4; ++j) b[j] = sk[r * 33 + w0 + 4 + j];
        __builtin_nontemporal_store(a, (ux4*)(P + base));
        __builtin_nontemporal_store(b, (ux4*)(P + base + 4));
    }
}

// ---- kernel 3: main. wave handles 8 o's; lane = 8*g + c; lane covers b=4c..4c+3
__global__ __launch_bounds__(256) void dsm_main(
    const ushort* __restrict__ xTh,   // fp16 [NI][NB]
    const uint*   __restrict__ P,     // [NO][NW] packed (i<<16 | h(s)), i-sorted
    float* __restrict__ out)          // [NB][NO]
{
    __shared__ uint sp[4][264];       // per-wave 8 o's, stride 33 (pad)
    const int tid = threadIdx.x;
    const int wave = tid >> 6;
    const int lane = tid & 63;
    const int g = lane >> 3;          // o sub-index within wave
    const int c = lane & 7;           // b-group: b = 4c..4c+3
    const int o_block = blockIdx.x * 32;
    const int o_wave = o_block + wave * 8;

    {
        const ux4 pv = __builtin_nontemporal_load(
            (const ux4*)(P + (size_t)o_wave * NW + lane * 4));
        const int lin = lane * 4;
#pragma unroll
        for (int j = 0; j < 4; ++j) {
            const int ol = (lin + j) >> 5, w = (lin + j) & 31;
            sp[wave][ol * 33 + w] = pv[j];
        }
    }
    __syncthreads();

    float acc0 = 0.f, acc1 = 0.f, acc2 = 0.f, acc3 = 0.f;
    const uint* spw = &sp[wave][g * 33];
#pragma unroll
    for (int w = 0; w < NW; ++w) {
        const uint p = spw[w];                      // broadcast, conflict-free
        const uint i = p >> 16;
        const float s = __half2float(__ushort_as_half((ushort)p));
        const ux2 xv = *(const ux2*)(xTh + i * NB + c * 4);  // 8B/lane
        const float x0 = __half2float(__ushort_as_half((ushort)(xv.x & 0xffffu)));
        const float x1 = __half2float(__ushort_as_half((ushort)(xv.x >> 16)));
        const float x2 = __half2float(__ushort_as_half((ushort)(xv.y & 0xffffu)));
        const float x3 = __half2float(__ushort_as_half((ushort)(xv.y >> 16)));
        acc0 = fmaf(s, x0, acc0);
        acc1 = fmaf(s, x1, acc1);
        acc2 = fmaf(s, x2, acc2);
        acc3 = fmaf(s, x3, acc3);
    }
    __syncthreads();                  // done reading sp; reuse as out tile

    float* tile = (float*)sp;         // [32][33]
    const int ocol = wave * 8 + g;
    tile[(4 * c + 0) * 33 + ocol] = acc0;
    tile[(4 * c + 1) * 33 + ocol] = acc1;
    tile[(4 * c + 2) * 33 + ocol] = acc2;
    tile[(4 * c + 3) * 33 + ocol] = acc3;
    __syncthreads();
#pragma unroll
    for (int r = 0; r < 4; ++r) {
        const int b = (tid >> 5) + 8 * r;
        __builtin_nontemporal_store(tile[b * 33 + (tid & 31)],
                                    &out[(size_t)b * NO + o_block + (tid & 31)]);
    }
}

// ---- fallback (no workspace): direct fp32, half-wave per o ----
__global__ __launch_bounds__(256) void dsm_fallback(
    const float* __restrict__ x, const float* __restrict__ fw,
    const float* __restrict__ fm, const int* __restrict__ om,
    const float* __restrict__ rm, float* __restrict__ out)
{
    const int tid = threadIdx.x;
    const int l = tid & 31, hw = tid >> 5;
    const int o = blockIdx.x * 8 + hw;
    const int i_l = om[(size_t)o * NW + l];
    const float s_l = fw[(size_t)i_l * NW + l] * fm[(size_t)i_l * NW + l]
                    * rm[(size_t)o * NW + l];
    float acc = 0.f;
#pragma unroll
    for (int w = 0; w < NW; ++w) {
        const int   i = __shfl(i_l, w, 32);
        const float s = __shfl(s_l, w, 32);
        acc = fmaf(s, x[(size_t)l * NI + i], acc);
    }
    out[(size_t)l * NO + o] = acc;
}

extern "C" void kernel_launch(void* const* d_in, const int* in_sizes, int n_in,
                              void* d_out, int out_size, void* d_ws, size_t ws_size,
                              hipStream_t stream) {
    const float* x  = (const float*)d_in[0];
    const float* fw = (const float*)d_in[1];
    const float* fm = (const float*)d_in[2];
    const int*   om = (const int*)d_in[3];
    const float* rm = (const float*)d_in[4];
    float* out = (float*)d_out;

    const size_t needP  = (size_t)NO * NW * sizeof(uint);    // 8 MB
    const size_t needXT = (size_t)NI * NB * sizeof(ushort);  // 4 MB
    const size_t needFW = (size_t)NI * NW * sizeof(ushort);  // 4 MB
    const size_t needFB = (size_t)NI * sizeof(uint);         // 256 KB

    if (ws_size >= needP + needXT + needFW + needFB) {
        uint*   P    = (uint*)d_ws;
        ushort* xTh  = (ushort*)((char*)d_ws + needP);
        ushort* fwmh = (ushort*)((char*)d_ws + needP + needXT);
        uint*   fmb  = (uint*)((char*)d_ws + needP + needXT + needFW);
        dsm_prep<<<dim3(NI / 32), 256, 0, stream>>>(x, fw, fm, xTh, fwmh);
        dsm_fmb<<<dim3(NI / 256), 256, 0, stream>>>(fm, fmb);
        dsm_pack<1><<<dim3(NO / 64), 256, 0, stream>>>(om, rm, fwmh, fmb, P);
        dsm_main<<<dim3(NO / 32), 256, 0, stream>>>(xTh, P, out);
    } else if (ws_size >= needP + needXT + needFW) {
        uint*   P    = (uint*)d_ws;
        ushort* xTh  = (ushort*)((char*)d_ws + needP);
        ushort* fwmh = (ushort*)((char*)d_ws + needP + needXT);
        dsm_prep<<<dim3(NI / 32), 256, 0, stream>>>(x, fw, fm, xTh, fwmh);
        dsm_pack<0><<<dim3(NO / 64), 256, 0, stream>>>(om, rm, fwmh, nullptr, P);
        dsm_main<<<dim3(NO / 32), 256, 0, stream>>>(xTh, P, out);
    } else {
        dsm_fallback<<<dim3(NO / 8), 256, 0, stream>>>(x, fw, fm, om, rm, out);
    }
}

// Round 6
// 55.620 us; speedup vs baseline: 1.0517x; 1.0517x over previous
//
#include <hip/hip_runtime.h>
#include <hip/hip_fp16.h>

#define NI 65536
#define NO 65536
#define NW 32
#define NB 32

typedef float  fx4 __attribute__((ext_vector_type(4)));
typedef int    ix4 __attribute__((ext_vector_type(4)));
typedef uint   ux4 __attribute__((ext_vector_type(4)));
typedef uint   ux2 __attribute__((ext_vector_type(2)));
typedef ushort sx4 __attribute__((ext_vector_type(4)));

// ---- kernel 1: xTh = fp16 transpose of x; fwmh = fp16(fw*fm); fmb bitmap ----
__global__ __launch_bounds__(256) void dsm_prep(
    const float* __restrict__ x, const float* __restrict__ fw,
    const float* __restrict__ fm, ushort* __restrict__ xTh,
    ushort* __restrict__ fwmh, uint* __restrict__ fmb)
{
    __shared__ float tile[32][33];
    __shared__ uint  lfmb[32];
    const int tid = threadIdx.x;
    const int tx = tid & 31, ty = tid >> 5;
    const int i0 = blockIdx.x * 32;

    if (tid < 32) lfmb[tid] = 0;
#pragma unroll
    for (int r = 0; r < 4; ++r) {
        const int b = ty + 8 * r;
        tile[b][tx] = __builtin_nontemporal_load(&x[(size_t)b * NI + i0 + tx]);
    }
    __syncthreads();
#pragma unroll
    for (int r = 0; r < 4; ++r) {
        const int ii = ty + 8 * r;
        xTh[(size_t)(i0 + ii) * NB + tx] =
            __half_as_ushort(__float2half(tile[tx][ii]));
    }
    // fw*fm -> fp16 (2048 blocks * 1024 elems = NI*NW) + fm bitmap
    const size_t base = (size_t)blockIdx.x * 1024 + (size_t)tid * 4;
    const fx4 a = __builtin_nontemporal_load((const fx4*)(fw + base));
    const fx4 m = __builtin_nontemporal_load((const fx4*)(fm + base));
    sx4 h;
    h.x = __half_as_ushort(__float2half(a.x * m.x));
    h.y = __half_as_ushort(__float2half(a.y * m.y));
    h.z = __half_as_ushort(__float2half(a.z * m.z));
    h.w = __half_as_ushort(__float2half(a.w * m.w));
    *(sx4*)(fwmh + base) = h;

    const uint bits = (m.x != 0.f ? 1u : 0u) | (m.y != 0.f ? 2u : 0u)
                    | (m.z != 0.f ? 4u : 0u) | (m.w != 0.f ? 8u : 0u);
    atomicOr(&lfmb[tid >> 3], bits << ((tid & 7) * 4));
    __syncthreads();
    if (tid < 32) fmb[blockIdx.x * 32 + tid] = lfmb[tid];
}

// ---- kernel 2: one thread per o-row. Drop rm=0 / fm=0 BEFORE gathering,
//      compact survivors to row front (order irrelevant), zero-pad, store. ----
template<int USE_FMB>
__global__ __launch_bounds__(256) void dsm_pack(
    const int* __restrict__ om, const float* __restrict__ rm,
    const ushort* __restrict__ fwmh, const uint* __restrict__ fmb,
    uint* __restrict__ P)
{
    __shared__ uint srow[256 * 33];   // per-thread indexable scratch row
    const int t = threadIdx.x;
    const size_t r = (size_t)blockIdx.x * 256 + t;
    const size_t ebase = r * NW;

    ix4 iv[8]; fx4 rv[8];
#pragma unroll
    for (int c = 0; c < 8; ++c) {
        iv[c] = __builtin_nontemporal_load((const ix4*)(om + ebase + c * 4));
        rv[c] = __builtin_nontemporal_load((const fx4*)(rm + ebase + c * 4));
    }
    uint* my = &srow[t * 33];
#pragma unroll
    for (int k = 0; k < 32; ++k) my[k] = 0;

    int cnt = 0;
#pragma unroll
    for (int c = 0; c < 8; ++c) {
#pragma unroll
        for (int j = 0; j < 4; ++j) {
            const int w = c * 4 + j;
            const uint i = (uint)iv[c][j] & 0xffffu;
            bool keep = (rv[c][j] != 0.0f);
            if (USE_FMB) keep = keep && (((fmb[i] >> w) & 1u) != 0u);
            if (keep) {
                const ushort hv = fwmh[i * NW + w];
                if (USE_FMB || (hv & 0x7fffu))
                    my[cnt++] = (i << 16) | (uint)hv;
            }
        }
    }
#pragma unroll
    for (int c = 0; c < 8; ++c) {
        ux4 v;
#pragma unroll
        for (int j = 0; j < 4; ++j) v[j] = my[c * 4 + j];
        __builtin_nontemporal_store(v, (ux4*)(P + ebase + c * 4));
    }
}

// ---- kernel 3: main. wave = 8 o's; lane = 8*g + c covers b=4c..4c+3.
//      Rows are compacted: break when all 8 rows exhausted. ----
__global__ __launch_bounds__(256) void dsm_main(
    const ushort* __restrict__ xTh,   // fp16 [NI][NB]
    const uint*   __restrict__ P,     // [NO][NW] packed (i<<16|h), compacted
    float* __restrict__ out)          // [NB][NO]
{
    __shared__ uint sp[4][264];       // per-wave 8 rows, stride 33
    const int tid = threadIdx.x;
    const int wave = tid >> 6;
    const int lane = tid & 63;
    const int g = lane >> 3;
    const int c = lane & 7;
    const int o_block = blockIdx.x * 32;
    const int o_wave = o_block + wave * 8;

    {
        const ux4 pv = __builtin_nontemporal_load(
            (const ux4*)(P + (size_t)o_wave * NW + lane * 4));
        const int lin = lane * 4;
#pragma unroll
        for (int j = 0; j < 4; ++j) {
            const int ol = (lin + j) >> 5, w = (lin + j) & 31;
            sp[wave][ol * 33 + w] = pv[j];
        }
    }
    __syncthreads();

    float acc0 = 0.f, acc1 = 0.f, acc2 = 0.f, acc3 = 0.f;
    const uint* spw = &sp[wave][g * 33];
#pragma unroll
    for (int wc = 0; wc < NW; wc += 8) {
        if (__all(spw[wc] == 0u)) break;   // all 8 rows exhausted (compacted)
#pragma unroll
        for (int w = wc; w < wc + 8; ++w) {
            const uint p = spw[w];
            const uint i = p >> 16;
            const float s = __half2float(__ushort_as_half((ushort)p));
            const ux2 xv = *(const ux2*)(xTh + i * NB + c * 4);
            const float x0 = __half2float(__ushort_as_half((ushort)(xv.x & 0xffffu)));
            const float x1 = __half2float(__ushort_as_half((ushort)(xv.x >> 16)));
            const float x2 = __half2float(__ushort_as_half((ushort)(xv.y & 0xffffu)));
            const float x3 = __half2float(__ushort_as_half((ushort)(xv.y >> 16)));
            acc0 = fmaf(s, x0, acc0);
            acc1 = fmaf(s, x1, acc1);
            acc2 = fmaf(s, x2, acc2);
            acc3 = fmaf(s, x3, acc3);
        }
    }
    __syncthreads();                  // reuse sp as out tile

    float* tile = (float*)sp;         // [32][33]
    const int ocol = wave * 8 + g;
    tile[(4 * c + 0) * 33 + ocol] = acc0;
    tile[(4 * c + 1) * 33 + ocol] = acc1;
    tile[(4 * c + 2) * 33 + ocol] = acc2;
    tile[(4 * c + 3) * 33 + ocol] = acc3;
    __syncthreads();
#pragma unroll
    for (int r = 0; r < 4; ++r) {
        const int b = (tid >> 5) + 8 * r;
        __builtin_nontemporal_store(tile[b * 33 + (tid & 31)],
                                    &out[(size_t)b * NO + o_block + (tid & 31)]);
    }
}

// ---- fallback (no workspace): direct fp32, half-wave per o ----
__global__ __launch_bounds__(256) void dsm_fallback(
    const float* __restrict__ x, const float* __restrict__ fw,
    const float* __restrict__ fm, const int* __restrict__ om,
    const float* __restrict__ rm, float* __restrict__ out)
{
    const int tid = threadIdx.x;
    const int l = tid & 31, hw = tid >> 5;
    const int o = blockIdx.x * 8 + hw;
    const int i_l = om[(size_t)o * NW + l];
    const float s_l = fw[(size_t)i_l * NW + l] * fm[(size_t)i_l * NW + l]
                    * rm[(size_t)o * NW + l];
    float acc = 0.f;
#pragma unroll
    for (int w = 0; w < NW; ++w) {
        const int   i = __shfl(i_l, w, 32);
        const float s = __shfl(s_l, w, 32);
        acc = fmaf(s, x[(size_t)l * NI + i], acc);
    }
    out[(size_t)l * NO + o] = acc;
}

extern "C" void kernel_launch(void* const* d_in, const int* in_sizes, int n_in,
                              void* d_out, int out_size, void* d_ws, size_t ws_size,
                              hipStream_t stream) {
    const float* x  = (const float*)d_in[0];
    const float* fw = (const float*)d_in[1];
    const float* fm = (const float*)d_in[2];
    const int*   om = (const int*)d_in[3];
    const float* rm = (const float*)d_in[4];
    float* out = (float*)d_out;

    const size_t needP  = (size_t)NO * NW * sizeof(uint);    // 8 MB
    const size_t needXT = (size_t)NI * NB * sizeof(ushort);  // 4 MB
    const size_t needFW = (size_t)NI * NW * sizeof(ushort);  // 4 MB
    const size_t needFB = (size_t)NI * sizeof(uint);         // 256 KB

    if (ws_size >= needP + needXT + needFW + needFB) {
        uint*   P    = (uint*)d_ws;
        ushort* xTh  = (ushort*)((char*)d_ws + needP);
        ushort* fwmh = (ushort*)((char*)d_ws + needP + needXT);
        uint*   fmb  = (uint*)((char*)d_ws + needP + needXT + needFW);
        dsm_prep<<<dim3(NI / 32), 256, 0, stream>>>(x, fw, fm, xTh, fwmh, fmb);
        dsm_pack<1><<<dim3(NO / 256), 256, 0, stream>>>(om, rm, fwmh, fmb, P);
        dsm_main<<<dim3(NO / 32), 256, 0, stream>>>(xTh, P, out);
    } else if (ws_size >= needP + needXT + needFW) {
        uint*   P    = (uint*)d_ws;
        ushort* xTh  = (ushort*)((char*)d_ws + needP);
        ushort* fwmh = (ushort*)((char*)d_ws + needP + needXT);
        // fmb omitted: prep still writes fwmh; pass fwmh as dummy fmb (unused)
        dsm_prep<<<dim3(NI / 32), 256, 0, stream>>>(x, fw, fm, xTh, fwmh,
                                                    (uint*)fwmh);
        dsm_pack<0><<<dim3(NO / 256), 256, 0, stream>>>(om, rm, fwmh, nullptr, P);
        dsm_main<<<dim3(NO / 32), 256, 0, stream>>>(xTh, P, out);
    } else {
        dsm_fallback<<<dim3(NO / 8), 256, 0, stream>>>(x, fw, fm, om, rm, out);
    }
}

// Round 7
// 54.500 us; speedup vs baseline: 1.0733x; 1.0205x over previous
//
#include <hip/hip_runtime.h>
#include <hip/hip_fp16.h>

#define NI 65536
#define NO 65536
#define NW 32
#define NB 32

typedef float  fx4 __attribute__((ext_vector_type(4)));
typedef int    ix4 __attribute__((ext_vector_type(4)));
typedef uint   ux4 __attribute__((ext_vector_type(4)));
typedef uint   ux2 __attribute__((ext_vector_type(2)));
typedef ushort sx4 __attribute__((ext_vector_type(4)));

// ---- kernel 1: xTh = fp16 transpose of x; fwmh = fp16(fw*fm); fmb bitmap ----
template<int WRITE_FMB>
__global__ __launch_bounds__(256) void dsm_prep(
    const float* __restrict__ x, const float* __restrict__ fw,
    const float* __restrict__ fm, ushort* __restrict__ xTh,
    ushort* __restrict__ fwmh, uint* __restrict__ fmb)
{
    __shared__ float tile[32][33];
    __shared__ uint  lfmb[32];
    const int tid = threadIdx.x;
    const int tx = tid & 31, ty = tid >> 5;
    const int i0 = blockIdx.x * 32;

    if (WRITE_FMB && tid < 32) lfmb[tid] = 0;
#pragma unroll
    for (int r = 0; r < 4; ++r) {
        const int b = ty + 8 * r;
        tile[b][tx] = __builtin_nontemporal_load(&x[(size_t)b * NI + i0 + tx]);
    }
    __syncthreads();
#pragma unroll
    for (int r = 0; r < 4; ++r) {
        const int ii = ty + 8 * r;
        xTh[(size_t)(i0 + ii) * NB + tx] =
            __half_as_ushort(__float2half(tile[tx][ii]));
    }
    // fw*fm -> fp16 (2048 blocks * 1024 elems = NI*NW) + fm bitmap
    const size_t base = (size_t)blockIdx.x * 1024 + (size_t)tid * 4;
    const fx4 a = __builtin_nontemporal_load((const fx4*)(fw + base));
    const fx4 m = __builtin_nontemporal_load((const fx4*)(fm + base));
    sx4 h;
    h.x = __half_as_ushort(__float2half(a.x * m.x));
    h.y = __half_as_ushort(__float2half(a.y * m.y));
    h.z = __half_as_ushort(__float2half(a.z * m.z));
    h.w = __half_as_ushort(__float2half(a.w * m.w));
    *(sx4*)(fwmh + base) = h;

    if (WRITE_FMB) {
        const uint bits = (m.x != 0.f ? 1u : 0u) | (m.y != 0.f ? 2u : 0u)
                        | (m.z != 0.f ? 4u : 0u) | (m.w != 0.f ? 8u : 0u);
        atomicOr(&lfmb[tid >> 3], bits << ((tid & 7) * 4));
        __syncthreads();
        if (tid < 32) fmb[blockIdx.x * 32 + tid] = lfmb[tid];
    }
}

// ---- kernel 2: one thread per o-row. Drop rm=0 / fm=0 BEFORE gathering,
//      compact survivors to row front (order irrelevant), zero-pad, store.
//      om/rm loads are PLAIN (each thread's row = one 128B line; L1 retains
//      it across the 8 sub-loads — nt here caused 8x over-fetch in round 6). ----
template<int USE_FMB>
__global__ __launch_bounds__(256) void dsm_pack(
    const int* __restrict__ om, const float* __restrict__ rm,
    const ushort* __restrict__ fwmh, const uint* __restrict__ fmb,
    uint* __restrict__ P)
{
    __shared__ uint srow[256 * 33];   // per-thread indexable scratch row
    const int t = threadIdx.x;
    const size_t r = (size_t)blockIdx.x * 256 + t;
    const size_t ebase = r * NW;

    ix4 iv[8]; fx4 rv[8];
#pragma unroll
    for (int c = 0; c < 8; ++c) {
        iv[c] = *(const ix4*)(om + ebase + c * 4);
        rv[c] = *(const fx4*)(rm + ebase + c * 4);
    }
    // unconditional fmb probes (hot 256KB table) — pipelinable
    uint fbits[8][4];
    if (USE_FMB) {
#pragma unroll
        for (int c = 0; c < 8; ++c)
#pragma unroll
            for (int j = 0; j < 4; ++j) {
                const uint i = (uint)iv[c][j] & 0xffffu;
                fbits[c][j] = (fmb[i] >> (c * 4 + j)) & 1u;
            }
    }
    uint* my = &srow[t * 33];
#pragma unroll
    for (int k = 0; k < 32; ++k) my[k] = 0;

    int cnt = 0;
#pragma unroll
    for (int c = 0; c < 8; ++c) {
#pragma unroll
        for (int j = 0; j < 4; ++j) {
            const int w = c * 4 + j;
            const uint i = (uint)iv[c][j] & 0xffffu;
            bool keep = (rv[c][j] != 0.0f);
            if (USE_FMB) keep = keep && (fbits[c][j] != 0u);
            if (keep) {
                const ushort hv = fwmh[i * NW + w];
                if (USE_FMB || (hv & 0x7fffu))
                    my[cnt++] = (i << 16) | (uint)hv;
            }
        }
    }
#pragma unroll
    for (int c = 0; c < 8; ++c) {
        ux4 v;
#pragma unroll
        for (int j = 0; j < 4; ++j) v[j] = my[c * 4 + j];
        __builtin_nontemporal_store(v, (ux4*)(P + ebase + c * 4));
    }
}

// ---- kernel 3: main. wave = 8 o's; lane = 8*g + c covers b=4c..4c+3.
//      Rows are compacted: break when all 8 rows exhausted. ----
__global__ __launch_bounds__(256) void dsm_main(
    const ushort* __restrict__ xTh,   // fp16 [NI][NB]
    const uint*   __restrict__ P,     // [NO][NW] packed (i<<16|h), compacted
    float* __restrict__ out)          // [NB][NO]
{
    __shared__ uint sp[4][264];       // per-wave 8 rows, stride 33
    const int tid = threadIdx.x;
    const int wave = tid >> 6;
    const int lane = tid & 63;
    const int g = lane >> 3;
    const int c = lane & 7;
    const int o_block = blockIdx.x * 32;
    const int o_wave = o_block + wave * 8;

    {
        const ux4 pv = __builtin_nontemporal_load(
            (const ux4*)(P + (size_t)o_wave * NW + lane * 4));
        const int lin = lane * 4;
#pragma unroll
        for (int j = 0; j < 4; ++j) {
            const int ol = (lin + j) >> 5, w = (lin + j) & 31;
            sp[wave][ol * 33 + w] = pv[j];
        }
    }
    __syncthreads();

    float acc0 = 0.f, acc1 = 0.f, acc2 = 0.f, acc3 = 0.f;
    const uint* spw = &sp[wave][g * 33];
#pragma unroll
    for (int wc = 0; wc < NW; wc += 8) {
        if (__all(spw[wc] == 0u)) break;   // all 8 rows exhausted (compacted)
#pragma unroll
        for (int w = wc; w < wc + 8; ++w) {
            const uint p = spw[w];
            const uint i = p >> 16;
            const float s = __half2float(__ushort_as_half((ushort)p));
            const ux2 xv = *(const ux2*)(xTh + i * NB + c * 4);
            const float x0 = __half2float(__ushort_as_half((ushort)(xv.x & 0xffffu)));
            const float x1 = __half2float(__ushort_as_half((ushort)(xv.x >> 16)));
            const float x2 = __half2float(__ushort_as_half((ushort)(xv.y & 0xffffu)));
            const float x3 = __half2float(__ushort_as_half((ushort)(xv.y >> 16)));
            acc0 = fmaf(s, x0, acc0);
            acc1 = fmaf(s, x1, acc1);
            acc2 = fmaf(s, x2, acc2);
            acc3 = fmaf(s, x3, acc3);
        }
    }
    __syncthreads();                  // reuse sp as out tile

    float* tile = (float*)sp;         // [32][33]
    const int ocol = wave * 8 + g;
    tile[(4 * c + 0) * 33 + ocol] = acc0;
    tile[(4 * c + 1) * 33 + ocol] = acc1;
    tile[(4 * c + 2) * 33 + ocol] = acc2;
    tile[(4 * c + 3) * 33 + ocol] = acc3;
    __syncthreads();
#pragma unroll
    for (int r = 0; r < 4; ++r) {
        const int b = (tid >> 5) + 8 * r;
        __builtin_nontemporal_store(tile[b * 33 + (tid & 31)],
                                    &out[(size_t)b * NO + o_block + (tid & 31)]);
    }
}

// ---- fallback (no workspace): direct fp32, half-wave per o ----
__global__ __launch_bounds__(256) void dsm_fallback(
    const float* __restrict__ x, const float* __restrict__ fw,
    const float* __restrict__ fm, const int* __restrict__ om,
    const float* __restrict__ rm, float* __restrict__ out)
{
    const int tid = threadIdx.x;
    const int l = tid & 31, hw = tid >> 5;
    const int o = blockIdx.x * 8 + hw;
    const int i_l = om[(size_t)o * NW + l];
    const float s_l = fw[(size_t)i_l * NW + l] * fm[(size_t)i_l * NW + l]
                    * rm[(size_t)o * NW + l];
    float acc = 0.f;
#pragma unroll
    for (int w = 0; w < NW; ++w) {
        const int   i = __shfl(i_l, w, 32);
        const float s = __shfl(s_l, w, 32);
        acc = fmaf(s, x[(size_t)l * NI + i], acc);
    }
    out[(size_t)l * NO + o] = acc;
}

extern "C" void kernel_launch(void* const* d_in, const int* in_sizes, int n_in,
                              void* d_out, int out_size, void* d_ws, size_t ws_size,
                              hipStream_t stream) {
    const float* x  = (const float*)d_in[0];
    const float* fw = (const float*)d_in[1];
    const float* fm = (const float*)d_in[2];
    const int*   om = (const int*)d_in[3];
    const float* rm = (const float*)d_in[4];
    float* out = (float*)d_out;

    const size_t needP  = (size_t)NO * NW * sizeof(uint);    // 8 MB
    const size_t needXT = (size_t)NI * NB * sizeof(ushort);  // 4 MB
    const size_t needFW = (size_t)NI * NW * sizeof(ushort);  // 4 MB
    const size_t needFB = (size_t)NI * sizeof(uint);         // 256 KB

    if (ws_size >= needP + needXT + needFW + needFB) {
        uint*   P    = (uint*)d_ws;
        ushort* xTh  = (ushort*)((char*)d_ws + needP);
        ushort* fwmh = (ushort*)((char*)d_ws + needP + needXT);
        uint*   fmb  = (uint*)((char*)d_ws + needP + needXT + needFW);
        dsm_prep<1><<<dim3(NI / 32), 256, 0, stream>>>(x, fw, fm, xTh, fwmh, fmb);
        dsm_pack<1><<<dim3(NO / 256), 256, 0, stream>>>(om, rm, fwmh, fmb, P);
        dsm_main<<<dim3(NO / 32), 256, 0, stream>>>(xTh, P, out);
    } else if (ws_size >= needP + needXT + needFW) {
        uint*   P    = (uint*)d_ws;
        ushort* xTh  = (ushort*)((char*)d_ws + needP);
        ushort* fwmh = (ushort*)((char*)d_ws + needP + needXT);
        dsm_prep<0><<<dim3(NI / 32), 256, 0, stream>>>(x, fw, fm, xTh, fwmh,
                                                       nullptr);
        dsm_pack<0><<<dim3(NO / 256), 256, 0, stream>>>(om, rm, fwmh, nullptr, P);
        dsm_main<<<dim3(NO / 32), 256, 0, stream>>>(xTh, P, out);
    } else {
        dsm_fallback<<<dim3(NO / 8), 256, 0, stream>>>(x, fw, fm, om, rm, out);
    }
}

// Round 8
// 41.651 us; speedup vs baseline: 1.4044x; 1.3085x over previous
//
#include <hip/hip_runtime.h>
#include <hip/hip_fp16.h>

#define NI 65536
#define NO 65536
#define NW 32
#define NB 32

typedef float  fx4 __attribute__((ext_vector_type(4)));
typedef int    ix4 __attribute__((ext_vector_type(4)));
typedef uint   ux4 __attribute__((ext_vector_type(4)));
typedef uint   ux2 __attribute__((ext_vector_type(2)));
typedef ushort sx4 __attribute__((ext_vector_type(4)));

// T[i] = 128B record: ushort[0:32) = x column i (fp16, b=0..31),
//                     ushort[32:64) = fp16(fw*fm) row i (w=0..31).
// fmb[i] bit w = (fm[i][w] != 0).

// ---- kernel 1: build T (interleaved) + fmb bitmap ----
__global__ __launch_bounds__(256) void dsm_prep(
    const float* __restrict__ x, const float* __restrict__ fw,
    const float* __restrict__ fm, ushort* __restrict__ T16,
    uint* __restrict__ fmb)
{
    __shared__ float tile[32][33];
    __shared__ uint  lfmb[32];
    const int tid = threadIdx.x;
    const int tx = tid & 31, ty = tid >> 5;
    const int i0 = blockIdx.x * 32;

    if (tid < 32) lfmb[tid] = 0;
#pragma unroll
    for (int r = 0; r < 4; ++r) {
        const int b = ty + 8 * r;
        tile[b][tx] = __builtin_nontemporal_load(&x[(size_t)b * NI + i0 + tx]);
    }
    __syncthreads();
#pragma unroll
    for (int r = 0; r < 4; ++r) {
        const int ii = ty + 8 * r;
        T16[(size_t)(i0 + ii) * 64 + tx] =
            __half_as_ushort(__float2half(tile[tx][ii]));
    }
    // fw*fm -> fp16 into T[row][32+w0..w0+3]; fm bitmap
    const size_t base = (size_t)blockIdx.x * 1024 + (size_t)tid * 4;
    const int row = i0 + (tid >> 3);
    const int w0  = (tid & 7) * 4;
    const fx4 a = __builtin_nontemporal_load((const fx4*)(fw + base));
    const fx4 m = __builtin_nontemporal_load((const fx4*)(fm + base));
    sx4 h;
    h.x = __half_as_ushort(__float2half(a.x * m.x));
    h.y = __half_as_ushort(__float2half(a.y * m.y));
    h.z = __half_as_ushort(__float2half(a.z * m.z));
    h.w = __half_as_ushort(__float2half(a.w * m.w));
    *(sx4*)(T16 + (size_t)row * 64 + 32 + w0) = h;

    const uint bits = (m.x != 0.f ? 1u : 0u) | (m.y != 0.f ? 2u : 0u)
                    | (m.z != 0.f ? 4u : 0u) | (m.w != 0.f ? 8u : 0u);
    atomicOr(&lfmb[tid >> 3], bits << w0);
    __syncthreads();
    if (tid < 32) fmb[blockIdx.x * 32 + tid] = lfmb[tid];
}

// ---- kernel 2 (fused main): phase A builds keys (om/rm coalesced + fmb
//      filter -> LDS); phase B w-loop with group-uniform masked 128B-record
//      gathers (s and x-row from the SAME line); out via LDS tile. ----
__global__ __launch_bounds__(256) void dsm_fused(
    const int*    __restrict__ om,
    const float*  __restrict__ rm,
    const ushort* __restrict__ T16,
    const uint*   __restrict__ fmb,
    float* __restrict__ out)          // [NB][NO]
{
    __shared__ uint sp[4][264];       // per-wave 8 rows, stride 33
    const int tid = threadIdx.x;
    const int wave = tid >> 6;
    const int lane = tid & 63;
    const int g = lane >> 3;          // o sub-index within wave
    const int c = lane & 7;           // b-group: b = 4c..4c+3
    const int o_block = blockIdx.x * 32;
    const int o_wave = o_block + wave * 8;

    // phase A: 8 o-rows = 256 entries; lane handles 4 consecutive entries
    {
        const size_t ebase = (size_t)o_wave * NW + (size_t)lane * 4;
        const ix4 iv = __builtin_nontemporal_load((const ix4*)(om + ebase));
        const fx4 rv = __builtin_nontemporal_load((const fx4*)(rm + ebase));
        const int lin = lane * 4;
        // unconditional fmb probes (256KB hot table) — 4 in flight
        uint fb[4];
#pragma unroll
        for (int j = 0; j < 4; ++j)
            fb[j] = fmb[(uint)iv[j] & 0xffffu];
#pragma unroll
        for (int j = 0; j < 4; ++j) {
            const int w = (lin + j) & 31;
            const uint i = (uint)iv[j] & 0xffffu;
            const uint keep = (rv[j] != 0.0f) & ((fb[j] >> w) & 1u);
            sp[wave][((lin + j) >> 5) * 33 + w] = keep ? ((i << 16) | 1u) : 0u;
        }
    }
    __syncthreads();

    // phase B: group-uniform skip; survivors read s + x-row from one 128B line
    float acc0 = 0.f, acc1 = 0.f, acc2 = 0.f, acc3 = 0.f;
    const uint* spw = &sp[wave][g * 33];
#pragma unroll
    for (int w = 0; w < NW; ++w) {
        const uint p = spw[w];
        if (p != 0u) {                 // uniform within 8-lane group
            const uint i = p >> 16;
            const ushort hs = T16[i * 64u + 32u + (uint)w];
            const float s = __half2float(__ushort_as_half(hs));
            const ux2 xv = *(const ux2*)(T16 + i * 64u + (uint)c * 4u);
            const float x0 = __half2float(__ushort_as_half((ushort)(xv.x & 0xffffu)));
            const float x1 = __half2float(__ushort_as_half((ushort)(xv.x >> 16)));
            const float x2 = __half2float(__ushort_as_half((ushort)(xv.y & 0xffffu)));
            const float x3 = __half2float(__ushort_as_half((ushort)(xv.y >> 16)));
            acc0 = fmaf(s, x0, acc0);
            acc1 = fmaf(s, x1, acc1);
            acc2 = fmaf(s, x2, acc2);
            acc3 = fmaf(s, x3, acc3);
        }
    }
    __syncthreads();                  // reuse sp as out tile

    float* tile = (float*)sp;         // [32][33]
    const int ocol = wave * 8 + g;
    tile[(4 * c + 0) * 33 + ocol] = acc0;
    tile[(4 * c + 1) * 33 + ocol] = acc1;
    tile[(4 * c + 2) * 33 + ocol] = acc2;
    tile[(4 * c + 3) * 33 + ocol] = acc3;
    __syncthreads();
#pragma unroll
    for (int r = 0; r < 4; ++r) {
        const int b = (tid >> 5) + 8 * r;
        __builtin_nontemporal_store(tile[b * 33 + (tid & 31)],
                                    &out[(size_t)b * NO + o_block + (tid & 31)]);
    }
}

// ---- fallback (no workspace): direct fp32, half-wave per o ----
__global__ __launch_bounds__(256) void dsm_fallback(
    const float* __restrict__ x, const float* __restrict__ fw,
    const float* __restrict__ fm, const int* __restrict__ om,
    const float* __restrict__ rm, float* __restrict__ out)
{
    const int tid = threadIdx.x;
    const int l = tid & 31, hw = tid >> 5;
    const int o = blockIdx.x * 8 + hw;
    const int i_l = om[(size_t)o * NW + l];
    const float s_l = fw[(size_t)i_l * NW + l] * fm[(size_t)i_l * NW + l]
                    * rm[(size_t)o * NW + l];
    float acc = 0.f;
#pragma unroll
    for (int w = 0; w < NW; ++w) {
        const int   i = __shfl(i_l, w, 32);
        const float s = __shfl(s_l, w, 32);
        acc = fmaf(s, x[(size_t)l * NI + i], acc);
    }
    out[(size_t)l * NO + o] = acc;
}

extern "C" void kernel_launch(void* const* d_in, const int* in_sizes, int n_in,
                              void* d_out, int out_size, void* d_ws, size_t ws_size,
                              hipStream_t stream) {
    const float* x  = (const float*)d_in[0];
    const float* fw = (const float*)d_in[1];
    const float* fm = (const float*)d_in[2];
    const int*   om = (const int*)d_in[3];
    const float* rm = (const float*)d_in[4];
    float* out = (float*)d_out;

    const size_t needT  = (size_t)NI * 64 * sizeof(ushort);  // 8 MB
    const size_t needFB = (size_t)NI * sizeof(uint);         // 256 KB

    if (ws_size >= needT + needFB) {
        ushort* T16 = (ushort*)d_ws;
        uint*   fmb = (uint*)((char*)d_ws + needT);
        dsm_prep<<<dim3(NI / 32), 256, 0, stream>>>(x, fw, fm, T16, fmb);
        dsm_fused<<<dim3(NO / 32), 256, 0, stream>>>(om, rm, T16, fmb, out);
    } else {
        dsm_fallback<<<dim3(NO / 8), 256, 0, stream>>>(x, fw, fm, om, rm, out);
    }
}

// Round 9
// 38.085 us; speedup vs baseline: 1.5359x; 1.0936x over previous
//
#include <hip/hip_runtime.h>
#include <hip/hip_fp16.h>

#define NI 65536
#define NO 65536
#define NW 32
#define NB 32

typedef float  fx4 __attribute__((ext_vector_type(4)));
typedef int    ix4 __attribute__((ext_vector_type(4)));
typedef uint   ux4 __attribute__((ext_vector_type(4)));
typedef uint   ux2 __attribute__((ext_vector_type(2)));
typedef ushort sx4 __attribute__((ext_vector_type(4)));

// ---- kernel 1: xTh = fp16 transpose of x [I][32]; fwmh = fp16(fw*fm) [I][32];
//      fmb[i] bit w = (fm[i][w] != 0) ----
__global__ __launch_bounds__(256) void dsm_prep(
    const float* __restrict__ x, const float* __restrict__ fw,
    const float* __restrict__ fm, ushort* __restrict__ xTh,
    ushort* __restrict__ fwmh, uint* __restrict__ fmb)
{
    __shared__ float tile[32][33];
    __shared__ uint  lfmb[32];
    const int tid = threadIdx.x;
    const int tx = tid & 31, ty = tid >> 5;
    const int i0 = blockIdx.x * 32;

    if (tid < 32) lfmb[tid] = 0;
#pragma unroll
    for (int r = 0; r < 4; ++r) {
        const int b = ty + 8 * r;
        tile[b][tx] = __builtin_nontemporal_load(&x[(size_t)b * NI + i0 + tx]);
    }
    __syncthreads();
#pragma unroll
    for (int r = 0; r < 4; ++r) {
        const int ii = ty + 8 * r;
        xTh[(size_t)(i0 + ii) * NB + tx] =
            __half_as_ushort(__float2half(tile[tx][ii]));
    }
    const size_t base = (size_t)blockIdx.x * 1024 + (size_t)tid * 4;
    const fx4 a = __builtin_nontemporal_load((const fx4*)(fw + base));
    const fx4 m = __builtin_nontemporal_load((const fx4*)(fm + base));
    sx4 h;
    h.x = __half_as_ushort(__float2half(a.x * m.x));
    h.y = __half_as_ushort(__float2half(a.y * m.y));
    h.z = __half_as_ushort(__float2half(a.z * m.z));
    h.w = __half_as_ushort(__float2half(a.w * m.w));
    *(sx4*)(fwmh + base) = h;

    const uint bits = (m.x != 0.f ? 1u : 0u) | (m.y != 0.f ? 2u : 0u)
                    | (m.z != 0.f ? 4u : 0u) | (m.w != 0.f ? 8u : 0u);
    atomicOr(&lfmb[tid >> 3], bits << ((tid & 7) * 4));
    __syncthreads();
    if (tid < 32) fmb[blockIdx.x * 32 + tid] = lfmb[tid];
}

// ---- kernel 2 (fused): phase A = filter + survivor-only fwmh gather +
//      ballot-compaction into LDS rows; phase B = dense chunked loop,
//      4 keys per ds_read_b128, 4 independent x-loads in flight. ----
__global__ __launch_bounds__(256) void dsm_fused(
    const int*    __restrict__ om,
    const float*  __restrict__ rm,
    const ushort* __restrict__ xTh,    // [NI][32] fp16
    const ushort* __restrict__ fwmh,   // [NI][32] fp16
    const uint*   __restrict__ fmb,    // [NI] bitmap
    float* __restrict__ out)           // [NB][NO]
{
    __shared__ uint sp[4][288];        // per-wave 8 rows, stride 36 (16B-aligned)
    const int tid  = threadIdx.x;
    const int wave = tid >> 6;
    const int lane = tid & 63;
    const int row  = lane >> 3;        // o sub-index within wave (0..7)
    const int c    = lane & 7;         // b-group: b = 4c..4c+3
    const int o_block = blockIdx.x * 32;
    const int o_wave  = o_block + wave * 8;

    // pre-zero this wave's sp segment (wave-local, in-order LDS)
#pragma unroll
    for (int k = lane; k < 288; k += 64) sp[wave][k] = 0;

    // ---- phase A: coalesced loads, filter, survivor gather, compaction ----
    int cnt = 0;
    {
        const size_t ebase = (size_t)o_wave * NW + (size_t)lane * 4;
        const ix4 iv = __builtin_nontemporal_load((const ix4*)(om + ebase));
        const fx4 rv = __builtin_nontemporal_load((const fx4*)(rm + ebase));
        const int w0 = (lane & 7) * 4;          // entry j has w = w0 + j
        uint fb[4];
#pragma unroll
        for (int j = 0; j < 4; ++j)
            fb[j] = fmb[(uint)iv[j] & 0xffffu];

        uint keep[4], key[4];
#pragma unroll
        for (int j = 0; j < 4; ++j) {
            const uint i = (uint)iv[j] & 0xffffu;
            keep[j] = (rv[j] != 0.0f) & ((fb[j] >> (w0 + j)) & 1u);
            key[j] = i << 16;
            if (keep[j])                         // survivor-only 2B gather
                key[j] |= (uint)fwmh[i * NW + w0 + j];
        }
        const unsigned long long rowmask  = 0xFFull << (row * 8);
        const unsigned long long beforeme = (lane == 63)
            ? 0x7FFFFFFFFFFFFFFFull : ((1ull << lane) - 1ull);
#pragma unroll
        for (int j = 0; j < 4; ++j) {
            const unsigned long long bl = __ballot(keep[j] != 0u);
            const int pos = cnt + __popcll(bl & rowmask & beforeme);
            if (keep[j]) sp[wave][row * 36 + pos] = key[j];
            cnt += __popcll(bl & rowmask);
        }
    }
    __syncthreads();

    // ---- phase B: dense compacted loop, 4-deep MLP ----
    float acc0 = 0.f, acc1 = 0.f, acc2 = 0.f, acc3 = 0.f;
    {
        const uint* spw = &sp[wave][row * 36];
        const int nw = (cnt + 3) & ~3;          // uniform within 8-lane group
        for (int t = 0; t < nw; t += 4) {
            const ux4 k4 = *(const ux4*)(spw + t);   // ds_read_b128 broadcast
#pragma unroll
            for (int j = 0; j < 4; ++j) {
                const uint p = k4[j];
                const uint i = p >> 16;
                const float s = __half2float(__ushort_as_half((ushort)(p & 0xffffu)));
                const ux2 xv = *(const ux2*)(xTh + i * NB + c * 4);
                const float x0 = __half2float(__ushort_as_half((ushort)(xv.x & 0xffffu)));
                const float x1 = __half2float(__ushort_as_half((ushort)(xv.x >> 16)));
                const float x2 = __half2float(__ushort_as_half((ushort)(xv.y & 0xffffu)));
                const float x3 = __half2float(__ushort_as_half((ushort)(xv.y >> 16)));
                acc0 = fmaf(s, x0, acc0);
                acc1 = fmaf(s, x1, acc1);
                acc2 = fmaf(s, x2, acc2);
                acc3 = fmaf(s, x3, acc3);
            }
        }
    }
    __syncthreads();                   // reuse sp as out tile

    float* tile = (float*)sp;          // flat 1152 uints >= 32*33
    const int ocol = wave * 8 + row;
    tile[(4 * c + 0) * 33 + ocol] = acc0;
    tile[(4 * c + 1) * 33 + ocol] = acc1;
    tile[(4 * c + 2) * 33 + ocol] = acc2;
    tile[(4 * c + 3) * 33 + ocol] = acc3;
    __syncthreads();
#pragma unroll
    for (int r = 0; r < 4; ++r) {
        const int b = (tid >> 5) + 8 * r;
        __builtin_nontemporal_store(tile[b * 33 + (tid & 31)],
                                    &out[(size_t)b * NO + o_block + (tid & 31)]);
    }
}

// ---- fallback (no workspace): direct fp32, half-wave per o ----
__global__ __launch_bounds__(256) void dsm_fallback(
    const float* __restrict__ x, const float* __restrict__ fw,
    const float* __restrict__ fm, const int* __restrict__ om,
    const float* __restrict__ rm, float* __restrict__ out)
{
    const int tid = threadIdx.x;
    const int l = tid & 31, hw = tid >> 5;
    const int o = blockIdx.x * 8 + hw;
    const int i_l = om[(size_t)o * NW + l];
    const float s_l = fw[(size_t)i_l * NW + l] * fm[(size_t)i_l * NW + l]
                    * rm[(size_t)o * NW + l];
    float acc = 0.f;
#pragma unroll
    for (int w = 0; w < NW; ++w) {
        const int   i = __shfl(i_l, w, 32);
        const float s = __shfl(s_l, w, 32);
        acc = fmaf(s, x[(size_t)l * NI + i], acc);
    }
    out[(size_t)l * NO + o] = acc;
}

extern "C" void kernel_launch(void* const* d_in, const int* in_sizes, int n_in,
                              void* d_out, int out_size, void* d_ws, size_t ws_size,
                              hipStream_t stream) {
    const float* x  = (const float*)d_in[0];
    const float* fw = (const float*)d_in[1];
    const float* fm = (const float*)d_in[2];
    const int*   om = (const int*)d_in[3];
    const float* rm = (const float*)d_in[4];
    float* out = (float*)d_out;

    const size_t needXT = (size_t)NI * NB * sizeof(ushort);  // 4 MB
    const size_t needFW = (size_t)NI * NW * sizeof(ushort);  // 4 MB
    const size_t needFB = (size_t)NI * sizeof(uint);         // 256 KB

    if (ws_size >= needXT + needFW + needFB) {
        ushort* xTh  = (ushort*)d_ws;
        ushort* fwmh = (ushort*)((char*)d_ws + needXT);
        uint*   fmb  = (uint*)((char*)d_ws + needXT + needFW);
        dsm_prep<<<dim3(NI / 32), 256, 0, stream>>>(x, fw, fm, xTh, fwmh, fmb);
        dsm_fused<<<dim3(NO / 32), 256, 0, stream>>>(om, rm, xTh, fwmh, fmb, out);
    } else {
        dsm_fallback<<<dim3(NO / 8), 256, 0, stream>>>(x, fw, fm, om, rm, out);
    }
}

// Round 10
// 36.502 us; speedup vs baseline: 1.6025x; 1.0434x over previous
//
#include <hip/hip_runtime.h>
#include <hip/hip_fp16.h>

#define NI 65536
#define NO 65536
#define NW 32
#define NB 32

typedef float  fx4 __attribute__((ext_vector_type(4)));
typedef float  fx2 __attribute__((ext_vector_type(2)));
typedef int    ix4 __attribute__((ext_vector_type(4)));
typedef uint   ux4 __attribute__((ext_vector_type(4)));
typedef ushort sx4 __attribute__((ext_vector_type(4)));

// ---- kernel 1: xTh = fp16 transpose of x [I][32]; fwmh = fp16(fw*fm) [I][32];
//      fmb[i] bit w = (fm[i][w] != 0) ----
__global__ __launch_bounds__(256) void dsm_prep(
    const float* __restrict__ x, const float* __restrict__ fw,
    const float* __restrict__ fm, ushort* __restrict__ xTh,
    ushort* __restrict__ fwmh, uint* __restrict__ fmb)
{
    __shared__ float tile[32][33];
    __shared__ uint  lfmb[32];
    const int tid = threadIdx.x;
    const int tx = tid & 31, ty = tid >> 5;
    const int i0 = blockIdx.x * 32;

    if (tid < 32) lfmb[tid] = 0;
#pragma unroll
    for (int r = 0; r < 4; ++r) {
        const int b = ty + 8 * r;
        tile[b][tx] = __builtin_nontemporal_load(&x[(size_t)b * NI + i0 + tx]);
    }
    __syncthreads();
#pragma unroll
    for (int r = 0; r < 4; ++r) {
        const int ii = ty + 8 * r;
        xTh[(size_t)(i0 + ii) * NB + tx] =
            __half_as_ushort(__float2half(tile[tx][ii]));
    }
    const size_t base = (size_t)blockIdx.x * 1024 + (size_t)tid * 4;
    const fx4 a = __builtin_nontemporal_load((const fx4*)(fw + base));
    const fx4 m = __builtin_nontemporal_load((const fx4*)(fm + base));
    sx4 h;
    h.x = __half_as_ushort(__float2half(a.x * m.x));
    h.y = __half_as_ushort(__float2half(a.y * m.y));
    h.z = __half_as_ushort(__float2half(a.z * m.z));
    h.w = __half_as_ushort(__float2half(a.w * m.w));
    *(sx4*)(fwmh + base) = h;

    const uint bits = (m.x != 0.f ? 1u : 0u) | (m.y != 0.f ? 2u : 0u)
                    | (m.z != 0.f ? 4u : 0u) | (m.w != 0.f ? 8u : 0u);
    atomicOr(&lfmb[tid >> 3], bits << ((tid & 7) * 4));
    __syncthreads();
    if (tid < 32) fmb[blockIdx.x * 32 + tid] = lfmb[tid];
}

// ---- kernel 2 (fused): wave = 16 o-rows x 4 lanes (16B/lane).
//      Phase A: filter + survivor-only fwmh gather + ballot compaction.
//      Phase B: dense chunked loop, 4 keys/ds_read_b128, 16B x-gathers,
//      float2 accumulators (v_pk_fma). Block = 64 o's. ----
__global__ __launch_bounds__(256) void dsm_fused(
    const int*    __restrict__ om,
    const float*  __restrict__ rm,
    const ushort* __restrict__ xTh,    // [NI][32] fp16
    const ushort* __restrict__ fwmh,   // [NI][32] fp16
    const uint*   __restrict__ fmb,    // [NI] bitmap
    float* __restrict__ out)           // [NB][NO]
{
    __shared__ uint sp[4][576];        // per-wave 16 rows, stride 36
    const int tid  = threadIdx.x;
    const int wave = tid >> 6;
    const int lane = tid & 63;
    const int row  = lane >> 2;        // o sub-index within wave (0..15)
    const int c    = lane & 3;         // 16B chunk: b = 8c..8c+7
    const int o_block = blockIdx.x * 64;
    const int o_wave  = o_block + wave * 16;

#pragma unroll
    for (int k = lane; k < 576; k += 64) sp[wave][k] = 0;

    // ---- phase A ----
    int cnt = 0;
    {
        const size_t ebase = (size_t)o_wave * NW + (size_t)lane * 8;
        const ix4 iv0 = __builtin_nontemporal_load((const ix4*)(om + ebase));
        const ix4 iv1 = __builtin_nontemporal_load((const ix4*)(om + ebase + 4));
        const fx4 rv0 = __builtin_nontemporal_load((const fx4*)(rm + ebase));
        const fx4 rv1 = __builtin_nontemporal_load((const fx4*)(rm + ebase + 4));
        const int w0 = c * 8;
        uint  ii[8]; float rr[8]; uint fb[8];
#pragma unroll
        for (int j = 0; j < 8; ++j) {
            ii[j] = (uint)((j < 4) ? iv0[j] : iv1[j - 4]) & 0xffffu;
            rr[j] = (j < 4) ? rv0[j] : rv1[j - 4];
        }
#pragma unroll
        for (int j = 0; j < 8; ++j) fb[j] = fmb[ii[j]];

        uint keep[8], key[8];
#pragma unroll
        for (int j = 0; j < 8; ++j) {
            keep[j] = (rr[j] != 0.0f) & ((fb[j] >> (w0 + j)) & 1u);
            key[j] = ii[j] << 16;
            if (keep[j])
                key[j] |= (uint)fwmh[ii[j] * NW + w0 + j];
        }
        const unsigned long long rowmask  = 0xFull << (row * 4);
        const unsigned long long beforeme = (1ull << lane) - 1ull;
#pragma unroll
        for (int j = 0; j < 8; ++j) {
            const unsigned long long bl = __ballot(keep[j] != 0u);
            const int pos = cnt + __popcll(bl & rowmask & beforeme);
            if (keep[j]) sp[wave][row * 36 + pos] = key[j];
            cnt += __popcll(bl & rowmask);
        }
    }
    __syncthreads();

    // ---- phase B ----
    fx2 a0 = {0.f, 0.f}, a1 = {0.f, 0.f}, a2 = {0.f, 0.f}, a3 = {0.f, 0.f};
    {
        const uint* spw = &sp[wave][row * 36];
        const int nw = (cnt + 3) & ~3;       // uniform within 4-lane group
        for (int t = 0; t < nw; t += 4) {
            const ux4 k4 = *(const ux4*)(spw + t);   // ds_read_b128 broadcast
#pragma unroll
            for (int j = 0; j < 4; ++j) {
                const uint p = k4[j];
                const uint i = p >> 16;
                const float sv = __half2float(__ushort_as_half((ushort)(p & 0xffffu)));
                const fx2 s2 = {sv, sv};
                const ux4 xv = *(const ux4*)(xTh + i * NB + c * 8);  // 16B/lane
#pragma unroll
                for (int k = 0; k < 4; ++k) {
                    fx2 xk;
                    xk.x = __half2float(__ushort_as_half((ushort)(xv[k] & 0xffffu)));
                    xk.y = __half2float(__ushort_as_half((ushort)(xv[k] >> 16)));
                    if (k == 0) a0 = s2 * xk + a0;
                    else if (k == 1) a1 = s2 * xk + a1;
                    else if (k == 2) a2 = s2 * xk + a2;
                    else a3 = s2 * xk + a3;
                }
            }
        }
    }
    __syncthreads();                   // all waves done with their sp segments

    // ---- epilogue: tile (32 b x 64 o-cols, stride 65) then coalesced store ----
    float* tile = (float*)sp;          // 2304 uints >= 32*65
    const int ocol = wave * 16 + row;
    tile[(c * 8 + 0) * 65 + ocol] = a0.x;
    tile[(c * 8 + 1) * 65 + ocol] = a0.y;
    tile[(c * 8 + 2) * 65 + ocol] = a1.x;
    tile[(c * 8 + 3) * 65 + ocol] = a1.y;
    tile[(c * 8 + 4) * 65 + ocol] = a2.x;
    tile[(c * 8 + 5) * 65 + ocol] = a2.y;
    tile[(c * 8 + 6) * 65 + ocol] = a3.x;
    tile[(c * 8 + 7) * 65 + ocol] = a3.y;
    __syncthreads();
    {
        const int col = tid & 63;
#pragma unroll
        for (int r = 0; r < 8; ++r) {
            const int b = (tid >> 6) + 4 * r;
            __builtin_nontemporal_store(tile[b * 65 + col],
                                        &out[(size_t)b * NO + o_block + col]);
        }
    }
}

// ---- fallback (no workspace): direct fp32, half-wave per o ----
__global__ __launch_bounds__(256) void dsm_fallback(
    const float* __restrict__ x, const float* __restrict__ fw,
    const float* __restrict__ fm, const int* __restrict__ om,
    const float* __restrict__ rm, float* __restrict__ out)
{
    const int tid = threadIdx.x;
    const int l = tid & 31, hw = tid >> 5;
    const int o = blockIdx.x * 8 + hw;
    const int i_l = om[(size_t)o * NW + l];
    const float s_l = fw[(size_t)i_l * NW + l] * fm[(size_t)i_l * NW + l]
                    * rm[(size_t)o * NW + l];
    float acc = 0.f;
#pragma unroll
    for (int w = 0; w < NW; ++w) {
        const int   i = __shfl(i_l, w, 32);
        const float s = __shfl(s_l, w, 32);
        acc = fmaf(s, x[(size_t)l * NI + i], acc);
    }
    out[(size_t)l * NO + o] = acc;
}

extern "C" void kernel_launch(void* const* d_in, const int* in_sizes, int n_in,
                              void* d_out, int out_size, void* d_ws, size_t ws_size,
                              hipStream_t stream) {
    const float* x  = (const float*)d_in[0];
    const float* fw = (const float*)d_in[1];
    const float* fm = (const float*)d_in[2];
    const int*   om = (const int*)d_in[3];
    const float* rm = (const float*)d_in[4];
    float* out = (float*)d_out;

    const size_t needXT = (size_t)NI * NB * sizeof(ushort);  // 4 MB
    const size_t needFW = (size_t)NI * NW * sizeof(ushort);  // 4 MB
    const size_t needFB = (size_t)NI * sizeof(uint);         // 256 KB

    if (ws_size >= needXT + needFW + needFB) {
        ushort* xTh  = (ushort*)d_ws;
        ushort* fwmh = (ushort*)((char*)d_ws + needXT);
        uint*   fmb  = (uint*)((char*)d_ws + needXT + needFW);
        dsm_prep<<<dim3(NI / 32), 256, 0, stream>>>(x, fw, fm, xTh, fwmh, fmb);
        dsm_fused<<<dim3(NO / 64), 256, 0, stream>>>(om, rm, xTh, fwmh, fmb, out);
    } else {
        dsm_fallback<<<dim3(NO / 8), 256, 0, stream>>>(x, fw, fm, om, rm, out);
    }
}

// Round 11
// 35.363 us; speedup vs baseline: 1.6541x; 1.0322x over previous
//
#include <hip/hip_runtime.h>
#include <hip/hip_fp16.h>

#define NI 65536
#define NO 65536
#define NW 32
#define NB 32

typedef float  fx4 __attribute__((ext_vector_type(4)));
typedef float  fx2 __attribute__((ext_vector_type(2)));
typedef int    ix4 __attribute__((ext_vector_type(4)));
typedef uint   ux4 __attribute__((ext_vector_type(4)));
typedef ushort sx4 __attribute__((ext_vector_type(4)));

// T[i] = 128B record (64 ushorts): [0:32) = x column i (fp16, b=0..31),
//                                  [32:64) = fp16(fw*fm) row i (w=0..31).
// fmb[i] bit w = (fm[i][w] != 0).

// ---- kernel 1: build T + fmb ----
__global__ __launch_bounds__(256) void dsm_prep(
    const float* __restrict__ x, const float* __restrict__ fw,
    const float* __restrict__ fm, ushort* __restrict__ T16,
    uint* __restrict__ fmb)
{
    __shared__ float tile[32][33];
    __shared__ uint  lfmb[32];
    const int tid = threadIdx.x;
    const int tx = tid & 31, ty = tid >> 5;
    const int i0 = blockIdx.x * 32;

    if (tid < 32) lfmb[tid] = 0;
#pragma unroll
    for (int r = 0; r < 4; ++r) {
        const int b = ty + 8 * r;
        tile[b][tx] = __builtin_nontemporal_load(&x[(size_t)b * NI + i0 + tx]);
    }
    __syncthreads();
#pragma unroll
    for (int r = 0; r < 4; ++r) {
        const int ii = ty + 8 * r;
        T16[(size_t)(i0 + ii) * 64 + tx] =
            __half_as_ushort(__float2half(tile[tx][ii]));
    }
    // fw*fm -> fp16 into record upper half; fm bitmap
    const size_t base = (size_t)blockIdx.x * 1024 + (size_t)tid * 4;
    const int row = i0 + (tid >> 3);
    const int w0  = (tid & 7) * 4;
    const fx4 a = __builtin_nontemporal_load((const fx4*)(fw + base));
    const fx4 m = __builtin_nontemporal_load((const fx4*)(fm + base));
    sx4 h;
    h.x = __half_as_ushort(__float2half(a.x * m.x));
    h.y = __half_as_ushort(__float2half(a.y * m.y));
    h.z = __half_as_ushort(__float2half(a.z * m.z));
    h.w = __half_as_ushort(__float2half(a.w * m.w));
    *(sx4*)(T16 + (size_t)row * 64 + 32 + w0) = h;

    const uint bits = (m.x != 0.f ? 1u : 0u) | (m.y != 0.f ? 2u : 0u)
                    | (m.z != 0.f ? 4u : 0u) | (m.w != 0.f ? 8u : 0u);
    atomicOr(&lfmb[tid >> 3], bits << w0);
    __syncthreads();
    if (tid < 32) fmb[blockIdx.x * 32 + tid] = lfmb[tid];
}

// ---- kernel 2 (fused): wave = 16 o-rows x 4 lanes (16B/lane).
//      Phase A: filter (fmb only, NO value gathers) + ballot compaction;
//      key = i<<16 | valid<<5 | w. Phase B: s and x from the SAME 128B
//      T-record line; float2 accumulators. Block = 64 o's. ----
__global__ __launch_bounds__(256) void dsm_fused(
    const int*    __restrict__ om,
    const float*  __restrict__ rm,
    const ushort* __restrict__ T16,    // [NI] 128B records
    const uint*   __restrict__ fmb,    // [NI] bitmap
    float* __restrict__ out)           // [NB][NO]
{
    __shared__ uint sp[4][576];        // per-wave 16 rows, stride 36
    const int tid  = threadIdx.x;
    const int wave = tid >> 6;
    const int lane = tid & 63;
    const int row  = lane >> 2;        // o sub-index within wave (0..15)
    const int c    = lane & 3;         // 16B chunk: b = 8c..8c+7
    const int o_block = blockIdx.x * 64;
    const int o_wave  = o_block + wave * 16;

#pragma unroll
    for (int k = lane; k < 576; k += 64) sp[wave][k] = 0;

    // ---- phase A: filter + compaction (no value gathers) ----
    int cnt = 0;
    {
        const size_t ebase = (size_t)o_wave * NW + (size_t)lane * 8;
        const ix4 iv0 = __builtin_nontemporal_load((const ix4*)(om + ebase));
        const ix4 iv1 = __builtin_nontemporal_load((const ix4*)(om + ebase + 4));
        const fx4 rv0 = __builtin_nontemporal_load((const fx4*)(rm + ebase));
        const fx4 rv1 = __builtin_nontemporal_load((const fx4*)(rm + ebase + 4));
        const int w0 = c * 8;
        uint  ii[8]; float rr[8]; uint fb[8];
#pragma unroll
        for (int j = 0; j < 8; ++j) {
            ii[j] = (uint)((j < 4) ? iv0[j] : iv1[j - 4]) & 0xffffu;
            rr[j] = (j < 4) ? rv0[j] : rv1[j - 4];
        }
#pragma unroll
        for (int j = 0; j < 8; ++j) fb[j] = fmb[ii[j]];

        const unsigned long long rowmask  = 0xFull << (row * 4);
        const unsigned long long beforeme = (1ull << lane) - 1ull;
#pragma unroll
        for (int j = 0; j < 8; ++j) {
            const uint keep = (rr[j] != 0.0f) & ((fb[j] >> (w0 + j)) & 1u);
            const unsigned long long bl = __ballot(keep != 0u);
            const int pos = cnt + __popcll(bl & rowmask & beforeme);
            if (keep)
                sp[wave][row * 36 + pos] = (ii[j] << 16) | 0x20u | (uint)(w0 + j);
            cnt += __popcll(bl & rowmask);
        }
    }
    __syncthreads();

    // ---- phase B: one 128B line per survivor (s + x同line), 4-deep MLP ----
    fx2 a0 = {0.f, 0.f}, a1 = {0.f, 0.f}, a2 = {0.f, 0.f}, a3 = {0.f, 0.f};
    {
        const uint* spw = &sp[wave][row * 36];
        const int nw = (cnt + 3) & ~3;       // uniform within 4-lane group
        for (int t = 0; t < nw; t += 4) {
            const ux4 k4 = *(const ux4*)(spw + t);   // ds_read_b128 broadcast
#pragma unroll
            for (int j = 0; j < 4; ++j) {
                const uint p = k4[j];
                const uint i = p >> 16;
                const uint w = p & 31u;
                float sv = __half2float(__ushort_as_half(T16[i * 64u + 32u + w]));
                sv = (p & 0x20u) ? sv : 0.0f;        // pad slots contribute 0
                const fx2 s2 = {sv, sv};
                const ux4 xv = *(const ux4*)(T16 + i * 64u + (uint)c * 8u);
#pragma unroll
                for (int k = 0; k < 4; ++k) {
                    fx2 xk;
                    xk.x = __half2float(__ushort_as_half((ushort)(xv[k] & 0xffffu)));
                    xk.y = __half2float(__ushort_as_half((ushort)(xv[k] >> 16)));
                    if (k == 0) a0 = s2 * xk + a0;
                    else if (k == 1) a1 = s2 * xk + a1;
                    else if (k == 2) a2 = s2 * xk + a2;
                    else a3 = s2 * xk + a3;
                }
            }
        }
    }
    __syncthreads();                   // all waves done with their sp segments

    // ---- epilogue: tile (32 b x 64 o-cols, stride 65) then coalesced store ----
    float* tile = (float*)sp;          // 2304 uints >= 32*65
    const int ocol = wave * 16 + row;
    tile[(c * 8 + 0) * 65 + ocol] = a0.x;
    tile[(c * 8 + 1) * 65 + ocol] = a0.y;
    tile[(c * 8 + 2) * 65 + ocol] = a1.x;
    tile[(c * 8 + 3) * 65 + ocol] = a1.y;
    tile[(c * 8 + 4) * 65 + ocol] = a2.x;
    tile[(c * 8 + 5) * 65 + ocol] = a2.y;
    tile[(c * 8 + 6) * 65 + ocol] = a3.x;
    tile[(c * 8 + 7) * 65 + ocol] = a3.y;
    __syncthreads();
    {
        const int col = tid & 63;
#pragma unroll
        for (int r = 0; r < 8; ++r) {
            const int b = (tid >> 6) + 4 * r;
            __builtin_nontemporal_store(tile[b * 65 + col],
                                        &out[(size_t)b * NO + o_block + col]);
        }
    }
}

// ---- fallback (no workspace): direct fp32, half-wave per o ----
__global__ __launch_bounds__(256) void dsm_fallback(
    const float* __restrict__ x, const float* __restrict__ fw,
    const float* __restrict__ fm, const int* __restrict__ om,
    const float* __restrict__ rm, float* __restrict__ out)
{
    const int tid = threadIdx.x;
    const int l = tid & 31, hw = tid >> 5;
    const int o = blockIdx.x * 8 + hw;
    const int i_l = om[(size_t)o * NW + l];
    const float s_l = fw[(size_t)i_l * NW + l] * fm[(size_t)i_l * NW + l]
                    * rm[(size_t)o * NW + l];
    float acc = 0.f;
#pragma unroll
    for (int w = 0; w < NW; ++w) {
        const int   i = __shfl(i_l, w, 32);
        const float s = __shfl(s_l, w, 32);
        acc = fmaf(s, x[(size_t)l * NI + i], acc);
    }
    out[(size_t)l * NO + o] = acc;
}

extern "C" void kernel_launch(void* const* d_in, const int* in_sizes, int n_in,
                              void* d_out, int out_size, void* d_ws, size_t ws_size,
                              hipStream_t stream) {
    const float* x  = (const float*)d_in[0];
    const float* fw = (const float*)d_in[1];
    const float* fm = (const float*)d_in[2];
    const int*   om = (const int*)d_in[3];
    const float* rm = (const float*)d_in[4];
    float* out = (float*)d_out;

    const size_t needT  = (size_t)NI * 64 * sizeof(ushort);  // 8 MB
    const size_t needFB = (size_t)NI * sizeof(uint);         // 256 KB

    if (ws_size >= needT + needFB) {
        ushort* T16 = (ushort*)d_ws;
        uint*   fmb = (uint*)((char*)d_ws + needT);
        dsm_prep<<<dim3(NI / 32), 256, 0, stream>>>(x, fw, fm, T16, fmb);
        dsm_fused<<<dim3(NO / 64), 256, 0, stream>>>(om, rm, T16, fmb, out);
    } else {
        dsm_fallback<<<dim3(NO / 8), 256, 0, stream>>>(x, fw, fm, om, rm, out);
    }
}